// Round 1
// baseline (22846.916 us; speedup 1.0000x reference)
//
#include <hip/hip_runtime.h>
#include <math.h>

#define HD    512
#define BATCH 256
#define TDIM  240
#define INDIM 300

// One LSTM timestep for up to 2 independent directions (blockIdx.z).
// Fused input projection: g = x[t] @ Wih^T + h @ Whh^T + bih + bhh.
// Column mapping: each thread owns one k (0..511) and the 4 gate quadrants
// {k, 512+k, 1024+k, 1536+k}, so the cell update is thread-local.
// h is double-buffered (hin -> hnew); c is updated in place (1 owner thread).
template<int BB>
__global__ __launch_bounds__(256) void lstm_step(
    const float* __restrict__ x,
    const float* __restrict__ Wih0, const float* __restrict__ Whh0,
    const float* __restrict__ bih0, const float* __restrict__ bhh0,
    const float* __restrict__ hin0, float* __restrict__ hnew0, float* __restrict__ cst0,
    float* __restrict__ ex0, int exs0, int tx0,
    const float* __restrict__ Wih1, const float* __restrict__ Whh1,
    const float* __restrict__ bih1, const float* __restrict__ bhh1,
    const float* __restrict__ hin1, float* __restrict__ hnew1, float* __restrict__ cst1,
    float* __restrict__ ex1, int exs1, int tx1)
{
    const int dir = blockIdx.z;
    const float* Wih = dir ? Wih1 : Wih0;
    const float* Whh = dir ? Whh1 : Whh0;
    const float* bih = dir ? bih1 : bih0;
    const float* bhh = dir ? bhh1 : bhh0;
    const float* hin = dir ? hin1 : hin0;
    float* hnew = dir ? hnew1 : hnew0;
    float* cst  = dir ? cst1  : cst0;
    float* ex   = dir ? ex1   : ex0;
    const int exs = dir ? exs1 : exs0;
    const int tx  = dir ? tx1  : tx0;

    const int bblk = blockIdx.x, kblk = blockIdx.y;
    const int tid = threadIdx.x;
    const int j  = tid & 15;   // k within block
    const int ty = tid >> 4;   // 0..15 batch-group
    const int k  = kblk * 16 + j;
    constexpr int RB = BB / 16;

    __shared__ float As[BB][33];   // [b][kk], pad to kill bank conflicts
    __shared__ float Bs[32][65];   // [kk][col]

    float acc[RB][4];
    #pragma unroll
    for (int r = 0; r < RB; ++r)
        #pragma unroll
        for (int q = 0; q < 4; ++q) acc[r][q] = 0.f;

    const int lb = tid >> 5, lk = tid & 31;  // loader mapping

    // ---- phase 0: input projection, K = 300 (zero-padded to 320) ----
    for (int kb = 0; kb < INDIM; kb += 32) {
        #pragma unroll
        for (int it = 0; it < BB/8; ++it) {
            int b = lb + it*8;
            int i = kb + lk;
            As[b][lk] = (i < INDIM) ? x[((bblk*BB + b)*TDIM + tx)*INDIM + i] : 0.f;
        }
        #pragma unroll
        for (int it = 0; it < 8; ++it) {
            int col = lb + it*8;
            int g = (col >> 4)*HD + kblk*16 + (col & 15);
            int i = kb + lk;
            Bs[lk][col] = (i < INDIM) ? Wih[g*INDIM + i] : 0.f;
        }
        __syncthreads();
        #pragma unroll
        for (int kk = 0; kk < 32; ++kk) {
            float a_[RB], b_[4];
            #pragma unroll
            for (int r = 0; r < RB; ++r) a_[r] = As[ty*RB + r][kk];
            #pragma unroll
            for (int q = 0; q < 4; ++q) b_[q] = Bs[kk][q*16 + j];
            #pragma unroll
            for (int r = 0; r < RB; ++r)
                #pragma unroll
                for (int q = 0; q < 4; ++q) acc[r][q] += a_[r]*b_[q];
        }
        __syncthreads();
    }

    // ---- phase 1: recurrent, K = 512 ----
    for (int kb = 0; kb < HD; kb += 32) {
        #pragma unroll
        for (int it = 0; it < BB/8; ++it) {
            int b = lb + it*8;
            As[b][lk] = hin[(bblk*BB + b)*HD + kb + lk];
        }
        #pragma unroll
        for (int it = 0; it < 8; ++it) {
            int col = lb + it*8;
            int g = (col >> 4)*HD + kblk*16 + (col & 15);
            Bs[lk][col] = Whh[g*HD + kb + lk];
        }
        __syncthreads();
        #pragma unroll
        for (int kk = 0; kk < 32; ++kk) {
            float a_[RB], b_[4];
            #pragma unroll
            for (int r = 0; r < RB; ++r) a_[r] = As[ty*RB + r][kk];
            #pragma unroll
            for (int q = 0; q < 4; ++q) b_[q] = Bs[kk][q*16 + j];
            #pragma unroll
            for (int r = 0; r < RB; ++r)
                #pragma unroll
                for (int q = 0; q < 4; ++q) acc[r][q] += a_[r]*b_[q];
        }
        __syncthreads();
    }

    // ---- epilogue: gates + cell update (thread-local) ----
    float bsum[4];
    #pragma unroll
    for (int q = 0; q < 4; ++q) bsum[q] = bih[q*HD + k] + bhh[q*HD + k];

    #pragma unroll
    for (int r = 0; r < RB; ++r) {
        int gb = bblk*BB + ty*RB + r;
        float iv = acc[r][0] + bsum[0];
        float fv = acc[r][1] + bsum[1];
        float gv = acc[r][2] + bsum[2];
        float ov = acc[r][3] + bsum[3];
        float cprev = cst[gb*HD + k];
        float si = 1.f/(1.f + expf(-iv));
        float sf = 1.f/(1.f + expf(-fv));
        float so = 1.f/(1.f + expf(-ov));
        float cn = sf*cprev + si*tanhf(gv);
        float hn = so*tanhf(cn);
        cst[gb*HD + k]  = cn;
        hnew[gb*HD + k] = hn;
        if (ex) ex[gb*exs + k] = hn;
    }
}

// C[m][n] = act(dot(A[m,:K], W[n,:K]) + bias[n]); tile 32x64.
// M = gridDim.x*32, N = gridDim.y*64.
template<int ACT>
__global__ __launch_bounds__(256) void gemm_bias_act(
    const float* __restrict__ A, int lda,
    const float* __restrict__ W,
    const float* __restrict__ bias,
    float* __restrict__ C, int ldc,
    int K)
{
    const int mblk = blockIdx.x, nblk = blockIdx.y;
    const int tid = threadIdx.x;
    const int txd = tid & 15, ty = tid >> 4;
    __shared__ float As[32][33];
    __shared__ float Bs[32][65];
    float acc[2][4] = {{0.f,0.f,0.f,0.f},{0.f,0.f,0.f,0.f}};
    const int lb = tid >> 5, lk = tid & 31;

    for (int kb = 0; kb < K; kb += 32) {
        #pragma unroll
        for (int it = 0; it < 4; ++it) {
            int r = lb + it*8;
            As[r][lk] = A[(mblk*32 + r)*lda + kb + lk];
        }
        #pragma unroll
        for (int it = 0; it < 8; ++it) {
            int col = lb + it*8;
            Bs[lk][col] = W[(nblk*64 + col)*K + kb + lk];
        }
        __syncthreads();
        #pragma unroll
        for (int kk = 0; kk < 32; ++kk) {
            float a0 = As[ty*2 + 0][kk], a1 = As[ty*2 + 1][kk];
            float b_[4];
            #pragma unroll
            for (int q = 0; q < 4; ++q) b_[q] = Bs[kk][q*16 + txd];
            #pragma unroll
            for (int q = 0; q < 4; ++q) { acc[0][q] += a0*b_[q]; acc[1][q] += a1*b_[q]; }
        }
        __syncthreads();
    }
    #pragma unroll
    for (int r = 0; r < 2; ++r) {
        int m = mblk*32 + ty*2 + r;
        #pragma unroll
        for (int q = 0; q < 4; ++q) {
            int n = nblk*64 + q*16 + txd;
            float v = acc[r][q] + (bias ? bias[n] : 0.f);
            if (ACT == 1) v = tanhf(v);
            C[m*ldc + n] = v;
        }
    }
}

// Per-batch: scores[t] = dot(title_out[b,t,:], u[b,:]) + bil_b; softmax over t;
// context[e] = sum_t p[t]*title_out[b,t,e] -> attn_in[b, 0:1024].
__global__ __launch_bounds__(256) void attn_ctx(
    const float* __restrict__ title_out,
    const float* __restrict__ u,
    const float* __restrict__ bilb,
    float* __restrict__ attn_in)
{
    int b = blockIdx.x;
    int tid = threadIdx.x;
    __shared__ float uL[1024];
    __shared__ float sc[40];
    for (int e = tid; e < 1024; e += 256) uL[e] = u[b*1024 + e];
    __syncthreads();
    int wave = tid >> 6, lane = tid & 63;
    for (int t = wave*10; t < wave*10 + 10; ++t) {
        const float* row = title_out + (b*40 + t)*1024;
        float s = 0.f;
        for (int e = lane; e < 1024; e += 64) s += row[e]*uL[e];
        #pragma unroll
        for (int off = 32; off > 0; off >>= 1) s += __shfl_down(s, off, 64);
        if (lane == 0) sc[t] = s + bilb[0];
    }
    __syncthreads();
    if (tid < 64) {
        float v = (tid < 40) ? sc[tid] : -1e30f;
        float m = v;
        #pragma unroll
        for (int off = 32; off > 0; off >>= 1) m = fmaxf(m, __shfl_xor(m, off, 64));
        float e = (tid < 40) ? expf(v - m) : 0.f;
        float ssum = e;
        #pragma unroll
        for (int off = 32; off > 0; off >>= 1) ssum += __shfl_xor(ssum, off, 64);
        if (tid < 40) sc[tid] = e / ssum;
    }
    __syncthreads();
    for (int e = tid; e < 1024; e += 256) {
        float a = 0.f;
        #pragma unroll
        for (int t = 0; t < 40; ++t) a += sc[t]*title_out[(b*40 + t)*1024 + e];
        attn_in[b*2048 + e] = a;
    }
}

__global__ void copy_rows(const float* __restrict__ src, int ss,
                          float* __restrict__ dst, int ds, int n)
{
    int b = blockIdx.x;
    for (int e = threadIdx.x; e < n; e += blockDim.x) dst[b*ds + e] = src[b*ss + e];
}

__global__ __launch_bounds__(64) void final_cls(
    const float* __restrict__ ch,
    const float* __restrict__ clsW,
    const float* __restrict__ clsb,
    float* __restrict__ out)
{
    int b = blockIdx.x*64 + threadIdx.x;
    float o[4];
    #pragma unroll
    for (int n = 0; n < 4; ++n) {
        float s = clsb[n];
        for (int jj = 0; jj < 512; ++jj) s += ch[b*512 + jj]*clsW[n*512 + jj];
        o[n] = s;
    }
    float m = fmaxf(fmaxf(o[0], o[1]), fmaxf(o[2], o[3]));
    float e0 = expf(o[0]-m), e1 = expf(o[1]-m), e2 = expf(o[2]-m), e3 = expf(o[3]-m);
    float s = e0 + e1 + e2 + e3;
    out[b*4+0] = e0/s; out[b*4+1] = e1/s; out[b*4+2] = e2/s; out[b*4+3] = e3/s;
}

extern "C" void kernel_launch(void* const* d_in, const int* in_sizes, int n_in,
                              void* d_out, int out_size, void* d_ws, size_t ws_size,
                              hipStream_t stream) {
    const float* x     = (const float*)d_in[0];
    const float* tWih  = (const float*)d_in[1];
    const float* tWhh  = (const float*)d_in[2];
    const float* tbih  = (const float*)d_in[3];
    const float* tbhh  = (const float*)d_in[4];
    const float* bWih  = (const float*)d_in[5];
    const float* bWhh  = (const float*)d_in[6];
    const float* bbih  = (const float*)d_in[7];
    const float* bbhh  = (const float*)d_in[8];
    const float* bilW  = (const float*)d_in[9];
    const float* bilb  = (const float*)d_in[10];
    const float* attnW = (const float*)d_in[11];
    const float* attnb = (const float*)d_in[12];
    const float* decW  = (const float*)d_in[13];
    const float* decb  = (const float*)d_in[14];
    const float* clsW  = (const float*)d_in[15];
    const float* clsb  = (const float*)d_in[16];

    // workspace layout (floats)
    float* p = (float*)d_ws;
    float* hA0 = p; p += BATCH*HD;     // zero-init block start
    float* c0  = p; p += BATCH*HD;
    float* hA1 = p; p += BATCH*HD;
    float* c1  = p; p += BATCH*HD;     // zero-init block end (4 buffers)
    float* hB0 = p; p += BATCH*HD;
    float* hB1 = p; p += BATCH*HD;
    float* title_out = p; p += BATCH*40*1024;
    float* body_last = p; p += BATCH*1024;
    float* u_buf     = p; p += BATCH*1024;
    float* attn_in   = p; p += BATCH*2048;
    float* out_cat   = p; p += BATCH*2048;
    float* ch        = p; p += BATCH*512;

    // h0 = c0 = 0 for both title directions (hA0,c0,hA1,c1 are contiguous)
    hipMemsetAsync(hA0, 0, (size_t)4*BATCH*HD*sizeof(float), stream);

    const float* tWih1 = tWih + 2048*INDIM;
    const float* tWhh1 = tWhh + 2048*HD;
    const float* bWih1 = bWih + 2048*INDIM;
    const float* bWhh1 = bWhh + 2048*HD;

    // ---- title: 40 steps, fwd + bwd concurrently ----
    for (int t = 0; t < 40; ++t) {
        float* hi0 = (t & 1) ? hB0 : hA0;
        float* ho0 = (t & 1) ? hA0 : hB0;
        float* hi1 = (t & 1) ? hB1 : hA1;
        float* ho1 = (t & 1) ? hA1 : hB1;
        lstm_step<64><<<dim3(4,32,2), 256, 0, stream>>>(
            x,
            tWih,  tWhh,  tbih,        tbhh,        hi0, ho0, c0,
            title_out + t*1024,            40*1024, t,
            tWih1, tWhh1, tbih + 2048, tbhh + 2048, hi1, ho1, c1,
            title_out + (39 - t)*1024 + 512, 40*1024, 39 - t);
    }
    // after step 39 the live state is in hA0 / hA1 (and c0 / c1)

    // ---- body step 0: fwd t=0  +  bwd single step at t=199 (tx=239) ----
    // (body backward output is only consumed at body_out[:, -1, :] == its first
    //  processed step, so the full 200-step backward scan is unnecessary)
    lstm_step<64><<<dim3(4,32,2), 256, 0, stream>>>(
        x,
        bWih,  bWhh,  bbih,        bbhh,        hA0, hB0, c0, (float*)nullptr, 0, 40,
        bWih1, bWhh1, bbih + 2048, bbhh + 2048, hA1, hB1, c1, body_last + 512, 1024, 239);

    // ---- body fwd steps 1..199 ----
    for (int t = 1; t < 200; ++t) {
        int s = 40 + t;
        float* hi = (s & 1) ? hB0 : hA0;
        float* ho = (s & 1) ? hA0 : hB0;
        float* ex = (t == 199) ? body_last : (float*)nullptr;
        lstm_step<32><<<dim3(8,32,1), 256, 0, stream>>>(
            x,
            bWih, bWhh, bbih, bbhh, hi, ho, c0, ex, 1024, 40 + t,
            nullptr, nullptr, nullptr, nullptr, nullptr, nullptr, nullptr,
            (float*)nullptr, 0, 0);
    }

    // ---- attention + classifier ----
    // u[b,e] = sum_h bil_W[0,e,h] * body_last[b,h]
    gemm_bias_act<0><<<dim3(8,16), 256, 0, stream>>>(body_last, 1024, bilW, nullptr,
                                                     u_buf, 1024, 1024);
    // scores -> softmax -> context (into attn_in[:, 0:1024])
    attn_ctx<<<256, 256, 0, stream>>>(title_out, u_buf, bilb, attn_in);
    // attn_in[:, 1024:2048] = body_last
    copy_rows<<<256, 256, 0, stream>>>(body_last, 1024, attn_in + 1024, 2048, 1024);
    // out_cat[:, 0:1024] = title_out[:, 39, :]
    copy_rows<<<256, 256, 0, stream>>>(title_out + 39*1024, 40*1024, out_cat, 2048, 1024);
    // out_cat[:, 1024:2048] = tanh(attn_in @ attn_W^T + attn_b)
    gemm_bias_act<1><<<dim3(8,16), 256, 0, stream>>>(attn_in, 2048, attnW, attnb,
                                                     out_cat + 1024, 2048, 2048);
    // ch = out_cat @ dec_W^T + dec_b
    gemm_bias_act<0><<<dim3(8,8), 256, 0, stream>>>(out_cat, 2048, decW, decb,
                                                    ch, 512, 2048);
    // logits + softmax -> d_out
    final_cls<<<4, 64, 0, stream>>>(ch, clsW, clsb, (float*)d_out);
}

// Round 2
// 7908.957 us; speedup vs baseline: 2.8887x; 2.8887x over previous
//
#include <hip/hip_runtime.h>
#include <math.h>

#define HD    512
#define BATCH 256
#define TDIM  240
#define INDIM 300
#define SLAB  524288   // 256*2048 floats, one (b,2048) timestep slab

// ============================================================================
// xg_gemm: out[t][b][2048] = x[b][toff+t0+t] @ Wih^T + bih + bhh
// 64 rows x 64 cols tile, K=300 (padded to 320 with guards).
// B-tile stored quadrant-interleaved: Bs[kk][j*4+q] = Wih[q*512+kblk*16+j][...]
// so each thread reads its 4 gate-quadrant weights as one float4.
// A-tile stored transposed: As[kk][b] so 4 batch rows read as one float4.
// ============================================================================
__global__ __launch_bounds__(256) void xg_gemm(
    const float* __restrict__ x,
    const float* __restrict__ Wih0, const float* __restrict__ bih0, const float* __restrict__ bhh0,
    float* __restrict__ out0,
    const float* __restrict__ Wih1, const float* __restrict__ bih1, const float* __restrict__ bhh1,
    float* __restrict__ out1,
    int t0, int toff)
{
    const int dir = blockIdx.z;
    const float* Wih = dir ? Wih1 : Wih0;
    const float* bih = dir ? bih1 : bih0;
    const float* bhh = dir ? bhh1 : bhh0;
    float* out = dir ? out1 : out0;

    const int rblk = blockIdx.x;
    const int tloc = rblk >> 2;          // slab index (t - t0)
    const int txx  = toff + t0 + tloc;   // absolute time index into x
    const int b0   = (rblk & 3) * 64;
    const int kblk = blockIdx.y;
    const int tid = threadIdx.x;
    const int j = tid & 15, ty = tid >> 4;
    const int lk = tid & 31, lw = tid >> 5;

    __shared__ __align__(16) float As[32][68];
    __shared__ __align__(16) float Bs[32][68];

    float acc[4][4] = {};
    for (int kb = 0; kb < 320; kb += 32) {
        const int i = kb + lk;
        const bool ok = (i < INDIM);
        #pragma unroll
        for (int it = 0; it < 8; ++it) {
            int b = lw + it * 8;
            As[lk][b] = ok ? x[((size_t)(b0 + b) * TDIM + txx) * INDIM + i] : 0.f;
        }
        #pragma unroll
        for (int it = 0; it < 8; ++it) {
            int c = lw + it * 8;
            int q = c & 3, jj = c >> 2;
            Bs[lk][c] = ok ? Wih[(size_t)(q * HD + kblk * 16 + jj) * INDIM + i] : 0.f;
        }
        __syncthreads();
        #pragma unroll
        for (int kk = 0; kk < 32; ++kk) {
            float4 av = *(const float4*)&As[kk][ty * 4];
            float4 bv = *(const float4*)&Bs[kk][j * 4];
            float a_[4] = {av.x, av.y, av.z, av.w};
            float b_[4] = {bv.x, bv.y, bv.z, bv.w};
            #pragma unroll
            for (int r = 0; r < 4; ++r)
                #pragma unroll
                for (int q = 0; q < 4; ++q) acc[r][q] += a_[r] * b_[q];
        }
        __syncthreads();
    }

    const int k = kblk * 16 + j;
    #pragma unroll
    for (int r = 0; r < 4; ++r) {
        int b = b0 + ty * 4 + r;
        size_t base = (size_t)tloc * SLAB + (size_t)b * 2048;
        #pragma unroll
        for (int q = 0; q < 4; ++q) {
            int col = q * HD + k;
            out[base + col] = acc[r][q] + bih[col] + bhh[col];
        }
    }
}

// ============================================================================
// lstm_step2: g = xg_t + h @ Whh^T ; cell update. Up to 2 dirs via blockIdx.z.
// Same vectorized LDS layout as xg_gemm. BB = batch tile (64 or 32).
// ============================================================================
template<int BB>
__global__ __launch_bounds__(256) void lstm_step2(
    const float* __restrict__ xg0, const float* __restrict__ Whh0,
    const float* __restrict__ hin0, float* __restrict__ hnew0, float* __restrict__ cst0,
    float* __restrict__ ex0, int exs0,
    const float* __restrict__ xg1, const float* __restrict__ Whh1,
    const float* __restrict__ hin1, float* __restrict__ hnew1, float* __restrict__ cst1,
    float* __restrict__ ex1, int exs1)
{
    const int dir = blockIdx.z;
    const float* xg  = dir ? xg1  : xg0;
    const float* Whh = dir ? Whh1 : Whh0;
    const float* hin = dir ? hin1 : hin0;
    float* hnew = dir ? hnew1 : hnew0;
    float* cst  = dir ? cst1  : cst0;
    float* ex   = dir ? ex1   : ex0;
    const int exs = dir ? exs1 : exs0;

    const int bblk = blockIdx.x, kblk = blockIdx.y;
    const int tid = threadIdx.x;
    const int j = tid & 15, ty = tid >> 4;
    const int lk = tid & 31, lw = tid >> 5;
    constexpr int RB = BB / 16;

    __shared__ __align__(16) float As[32][BB + 4];
    __shared__ __align__(16) float Bs[32][68];

    float acc[RB][4] = {};
    for (int kb = 0; kb < HD; kb += 32) {
        #pragma unroll
        for (int it = 0; it < BB / 8; ++it) {
            int b = lw + it * 8;
            As[lk][b] = hin[(size_t)(bblk * BB + b) * HD + kb + lk];
        }
        #pragma unroll
        for (int it = 0; it < 8; ++it) {
            int c = lw + it * 8;
            int q = c & 3, jj = c >> 2;
            Bs[lk][c] = Whh[(size_t)(q * HD + kblk * 16 + jj) * HD + kb + lk];
        }
        __syncthreads();
        #pragma unroll
        for (int kk = 0; kk < 32; ++kk) {
            float4 bv = *(const float4*)&Bs[kk][j * 4];
            float b_[4] = {bv.x, bv.y, bv.z, bv.w};
            float a_[RB];
            if constexpr (RB == 4) {
                float4 av = *(const float4*)&As[kk][ty * 4];
                a_[0] = av.x; a_[1] = av.y; a_[2] = av.z; a_[3] = av.w;
            } else {
                float2 av = *(const float2*)&As[kk][ty * 2];
                a_[0] = av.x; a_[1] = av.y;
            }
            #pragma unroll
            for (int r = 0; r < RB; ++r)
                #pragma unroll
                for (int q = 0; q < 4; ++q) acc[r][q] += a_[r] * b_[q];
        }
        __syncthreads();
    }

    const int k = kblk * 16 + j;
    #pragma unroll
    for (int r = 0; r < RB; ++r) {
        int gb = bblk * BB + ty * RB + r;
        size_t base = (size_t)gb * 2048 + k;
        float iv = acc[r][0] + xg[base];
        float fv = acc[r][1] + xg[base + 512];
        float gv = acc[r][2] + xg[base + 1024];
        float ov = acc[r][3] + xg[base + 1536];
        float cprev = cst[(size_t)gb * HD + k];
        float si = 1.f / (1.f + expf(-iv));
        float sf = 1.f / (1.f + expf(-fv));
        float so = 1.f / (1.f + expf(-ov));
        float cn = sf * cprev + si * tanhf(gv);
        float hn = so * tanhf(cn);
        cst[(size_t)gb * HD + k]  = cn;
        hnew[(size_t)gb * HD + k] = hn;
        if (ex) ex[(size_t)gb * exs + k] = hn;
    }
}

// ============================================================================
// Legacy fused step (x-projection inline) — fallback when ws_size is small.
// ============================================================================
template<int BB>
__global__ __launch_bounds__(256) void lstm_step(
    const float* __restrict__ x,
    const float* __restrict__ Wih0, const float* __restrict__ Whh0,
    const float* __restrict__ bih0, const float* __restrict__ bhh0,
    const float* __restrict__ hin0, float* __restrict__ hnew0, float* __restrict__ cst0,
    float* __restrict__ ex0, int exs0, int tx0,
    const float* __restrict__ Wih1, const float* __restrict__ Whh1,
    const float* __restrict__ bih1, const float* __restrict__ bhh1,
    const float* __restrict__ hin1, float* __restrict__ hnew1, float* __restrict__ cst1,
    float* __restrict__ ex1, int exs1, int tx1)
{
    const int dir = blockIdx.z;
    const float* Wih = dir ? Wih1 : Wih0;
    const float* Whh = dir ? Whh1 : Whh0;
    const float* bih = dir ? bih1 : bih0;
    const float* bhh = dir ? bhh1 : bhh0;
    const float* hin = dir ? hin1 : hin0;
    float* hnew = dir ? hnew1 : hnew0;
    float* cst  = dir ? cst1  : cst0;
    float* ex   = dir ? ex1   : ex0;
    const int exs = dir ? exs1 : exs0;
    const int tx  = dir ? tx1  : tx0;

    const int bblk = blockIdx.x, kblk = blockIdx.y;
    const int tid = threadIdx.x;
    const int j  = tid & 15;
    const int ty = tid >> 4;
    const int k  = kblk * 16 + j;
    constexpr int RB = BB / 16;

    __shared__ float As[BB][33];
    __shared__ float Bs[32][65];

    float acc[RB][4];
    #pragma unroll
    for (int r = 0; r < RB; ++r)
        #pragma unroll
        for (int q = 0; q < 4; ++q) acc[r][q] = 0.f;

    const int lb = tid >> 5, lk = tid & 31;

    for (int kb = 0; kb < INDIM; kb += 32) {
        #pragma unroll
        for (int it = 0; it < BB/8; ++it) {
            int b = lb + it*8;
            int i = kb + lk;
            As[b][lk] = (i < INDIM) ? x[((bblk*BB + b)*TDIM + tx)*INDIM + i] : 0.f;
        }
        #pragma unroll
        for (int it = 0; it < 8; ++it) {
            int col = lb + it*8;
            int g = (col >> 4)*HD + kblk*16 + (col & 15);
            int i = kb + lk;
            Bs[lk][col] = (i < INDIM) ? Wih[g*INDIM + i] : 0.f;
        }
        __syncthreads();
        #pragma unroll
        for (int kk = 0; kk < 32; ++kk) {
            float a_[RB], b_[4];
            #pragma unroll
            for (int r = 0; r < RB; ++r) a_[r] = As[ty*RB + r][kk];
            #pragma unroll
            for (int q = 0; q < 4; ++q) b_[q] = Bs[kk][q*16 + j];
            #pragma unroll
            for (int r = 0; r < RB; ++r)
                #pragma unroll
                for (int q = 0; q < 4; ++q) acc[r][q] += a_[r]*b_[q];
        }
        __syncthreads();
    }
    for (int kb = 0; kb < HD; kb += 32) {
        #pragma unroll
        for (int it = 0; it < BB/8; ++it) {
            int b = lb + it*8;
            As[b][lk] = hin[(bblk*BB + b)*HD + kb + lk];
        }
        #pragma unroll
        for (int it = 0; it < 8; ++it) {
            int col = lb + it*8;
            int g = (col >> 4)*HD + kblk*16 + (col & 15);
            Bs[lk][col] = Whh[g*HD + kb + lk];
        }
        __syncthreads();
        #pragma unroll
        for (int kk = 0; kk < 32; ++kk) {
            float a_[RB], b_[4];
            #pragma unroll
            for (int r = 0; r < RB; ++r) a_[r] = As[ty*RB + r][kk];
            #pragma unroll
            for (int q = 0; q < 4; ++q) b_[q] = Bs[kk][q*16 + j];
            #pragma unroll
            for (int r = 0; r < RB; ++r)
                #pragma unroll
                for (int q = 0; q < 4; ++q) acc[r][q] += a_[r]*b_[q];
        }
        __syncthreads();
    }
    float bsum[4];
    #pragma unroll
    for (int q = 0; q < 4; ++q) bsum[q] = bih[q*HD + k] + bhh[q*HD + k];
    #pragma unroll
    for (int r = 0; r < RB; ++r) {
        int gb = bblk*BB + ty*RB + r;
        float iv = acc[r][0] + bsum[0];
        float fv = acc[r][1] + bsum[1];
        float gv = acc[r][2] + bsum[2];
        float ov = acc[r][3] + bsum[3];
        float cprev = cst[gb*HD + k];
        float si = 1.f/(1.f + expf(-iv));
        float sf = 1.f/(1.f + expf(-fv));
        float so = 1.f/(1.f + expf(-ov));
        float cn = sf*cprev + si*tanhf(gv);
        float hn = so*tanhf(cn);
        cst[gb*HD + k]  = cn;
        hnew[gb*HD + k] = hn;
        if (ex) ex[gb*exs + k] = hn;
    }
}

// ============================================================================
// Epilogue kernels (unchanged, verified absmax 0.0)
// ============================================================================
template<int ACT>
__global__ __launch_bounds__(256) void gemm_bias_act(
    const float* __restrict__ A, int lda,
    const float* __restrict__ W,
    const float* __restrict__ bias,
    float* __restrict__ C, int ldc,
    int K)
{
    const int mblk = blockIdx.x, nblk = blockIdx.y;
    const int tid = threadIdx.x;
    const int txd = tid & 15, ty = tid >> 4;
    __shared__ float As[32][33];
    __shared__ float Bs[32][65];
    float acc[2][4] = {{0.f,0.f,0.f,0.f},{0.f,0.f,0.f,0.f}};
    const int lb = tid >> 5, lk = tid & 31;

    for (int kb = 0; kb < K; kb += 32) {
        #pragma unroll
        for (int it = 0; it < 4; ++it) {
            int r = lb + it*8;
            As[r][lk] = A[(mblk*32 + r)*lda + kb + lk];
        }
        #pragma unroll
        for (int it = 0; it < 8; ++it) {
            int col = lb + it*8;
            Bs[lk][col] = W[(nblk*64 + col)*K + kb + lk];
        }
        __syncthreads();
        #pragma unroll
        for (int kk = 0; kk < 32; ++kk) {
            float a0 = As[ty*2 + 0][kk], a1 = As[ty*2 + 1][kk];
            float b_[4];
            #pragma unroll
            for (int q = 0; q < 4; ++q) b_[q] = Bs[kk][q*16 + txd];
            #pragma unroll
            for (int q = 0; q < 4; ++q) { acc[0][q] += a0*b_[q]; acc[1][q] += a1*b_[q]; }
        }
        __syncthreads();
    }
    #pragma unroll
    for (int r = 0; r < 2; ++r) {
        int m = mblk*32 + ty*2 + r;
        #pragma unroll
        for (int q = 0; q < 4; ++q) {
            int n = nblk*64 + q*16 + txd;
            float v = acc[r][q] + (bias ? bias[n] : 0.f);
            if (ACT == 1) v = tanhf(v);
            C[m*ldc + n] = v;
        }
    }
}

__global__ __launch_bounds__(256) void attn_ctx(
    const float* __restrict__ title_out,
    const float* __restrict__ u,
    const float* __restrict__ bilb,
    float* __restrict__ attn_in)
{
    int b = blockIdx.x;
    int tid = threadIdx.x;
    __shared__ float uL[1024];
    __shared__ float sc[40];
    for (int e = tid; e < 1024; e += 256) uL[e] = u[b*1024 + e];
    __syncthreads();
    int wave = tid >> 6, lane = tid & 63;
    for (int t = wave*10; t < wave*10 + 10; ++t) {
        const float* row = title_out + (b*40 + t)*1024;
        float s = 0.f;
        for (int e = lane; e < 1024; e += 64) s += row[e]*uL[e];
        #pragma unroll
        for (int off = 32; off > 0; off >>= 1) s += __shfl_down(s, off, 64);
        if (lane == 0) sc[t] = s + bilb[0];
    }
    __syncthreads();
    if (tid < 64) {
        float v = (tid < 40) ? sc[tid] : -1e30f;
        float m = v;
        #pragma unroll
        for (int off = 32; off > 0; off >>= 1) m = fmaxf(m, __shfl_xor(m, off, 64));
        float e = (tid < 40) ? expf(v - m) : 0.f;
        float ssum = e;
        #pragma unroll
        for (int off = 32; off > 0; off >>= 1) ssum += __shfl_xor(ssum, off, 64);
        if (tid < 40) sc[tid] = e / ssum;
    }
    __syncthreads();
    for (int e = tid; e < 1024; e += 256) {
        float a = 0.f;
        #pragma unroll
        for (int t = 0; t < 40; ++t) a += sc[t]*title_out[(b*40 + t)*1024 + e];
        attn_in[b*2048 + e] = a;
    }
}

__global__ void copy_rows(const float* __restrict__ src, int ss,
                          float* __restrict__ dst, int ds, int n)
{
    int b = blockIdx.x;
    for (int e = threadIdx.x; e < n; e += blockDim.x) dst[b*ds + e] = src[b*ss + e];
}

__global__ __launch_bounds__(64) void final_cls(
    const float* __restrict__ ch,
    const float* __restrict__ clsW,
    const float* __restrict__ clsb,
    float* __restrict__ out)
{
    int b = blockIdx.x*64 + threadIdx.x;
    float o[4];
    #pragma unroll
    for (int n = 0; n < 4; ++n) {
        float s = clsb[n];
        for (int jj = 0; jj < 512; ++jj) s += ch[b*512 + jj]*clsW[n*512 + jj];
        o[n] = s;
    }
    float m = fmaxf(fmaxf(o[0], o[1]), fmaxf(o[2], o[3]));
    float e0 = expf(o[0]-m), e1 = expf(o[1]-m), e2 = expf(o[2]-m), e3 = expf(o[3]-m);
    float s = e0 + e1 + e2 + e3;
    out[b*4+0] = e0/s; out[b*4+1] = e1/s; out[b*4+2] = e2/s; out[b*4+3] = e3/s;
}

extern "C" void kernel_launch(void* const* d_in, const int* in_sizes, int n_in,
                              void* d_out, int out_size, void* d_ws, size_t ws_size,
                              hipStream_t stream) {
    const float* x     = (const float*)d_in[0];
    const float* tWih  = (const float*)d_in[1];
    const float* tWhh  = (const float*)d_in[2];
    const float* tbih  = (const float*)d_in[3];
    const float* tbhh  = (const float*)d_in[4];
    const float* bWih  = (const float*)d_in[5];
    const float* bWhh  = (const float*)d_in[6];
    const float* bbih  = (const float*)d_in[7];
    const float* bbhh  = (const float*)d_in[8];
    const float* bilW  = (const float*)d_in[9];
    const float* bilb  = (const float*)d_in[10];
    const float* attnW = (const float*)d_in[11];
    const float* attnb = (const float*)d_in[12];
    const float* decW  = (const float*)d_in[13];
    const float* decb  = (const float*)d_in[14];
    const float* clsW  = (const float*)d_in[15];
    const float* clsb  = (const float*)d_in[16];

    const float* tWih1 = tWih + 2048*INDIM;
    const float* tWhh1 = tWhh + 2048*HD;
    const float* bWih1 = bWih + 2048*INDIM;
    const float* bWhh1 = bWhh + 2048*HD;

    // ---- workspace layout (floats) ----
    float* p = (float*)d_ws;
    float* hA0 = p; p += BATCH*HD;
    float* c0  = p; p += BATCH*HD;
    float* hA1 = p; p += BATCH*HD;
    float* c1  = p; p += BATCH*HD;
    float* hB0 = p; p += BATCH*HD;
    float* hB1 = p; p += BATCH*HD;
    float* title_out = p; p += BATCH*40*1024;
    float* body_last = p; p += BATCH*1024;
    float* u_buf     = p; p += BATCH*1024;
    float* attn_in   = p; p += BATCH*2048;
    float* out_cat   = p; p += BATCH*2048;
    float* ch        = p; p += BATCH*512;
    float* xgT0      = p; p += 40*SLAB;
    float* xgT1      = p; p += 40*SLAB;
    float* xgBb      = p; p += SLAB;
    float* bodybuf   = p;   // body xg: full (200 slabs) or ring (2*C slabs)
    size_t fixed_floats = (size_t)(bodybuf - (float*)d_ws);

    // decide path from ws_size
    size_t ws_floats = ws_size / 4;
    bool use_new = false, full = false;
    int C = 0;
    if (ws_floats >= fixed_floats + 2*SLAB) {
        size_t nslab = (ws_floats - fixed_floats) / SLAB;
        if (nslab >= 200) { full = true; C = 200; }
        else { C = (int)((nslab/2 > 100) ? 100 : nslab/2); }
        use_new = (C >= 1);
    }

    hipMemsetAsync(hA0, 0, (size_t)4*BATCH*HD*sizeof(float), stream);

    if (use_new) {
        // ---- precompute input projections ----
        // title fwd+bwd xg, all 40 steps, both dirs
        xg_gemm<<<dim3(160,32,2), 256, 0, stream>>>(
            x, tWih, tbih, tbhh, xgT0,
               tWih1, tbih + 2048, tbhh + 2048, xgT1, 0, 0);
        // body bwd single step (t=239) with dir-1 weights
        xg_gemm<<<dim3(4,32,1), 256, 0, stream>>>(
            x, bWih1, bbih + 2048, bbhh + 2048, xgBb,
               bWih1, bbih + 2048, bbhh + 2048, xgBb, 0, 239);
        if (full) {
            xg_gemm<<<dim3(800,32,1), 256, 0, stream>>>(
                x, bWih, bbih, bbhh, bodybuf,
                   bWih, bbih, bbhh, bodybuf, 0, 40);
        }

        // ---- title: 40 steps, fwd + bwd concurrently ----
        for (int t = 0; t < 40; ++t) {
            float* hi0 = (t & 1) ? hB0 : hA0;
            float* ho0 = (t & 1) ? hA0 : hB0;
            float* hi1 = (t & 1) ? hB1 : hA1;
            float* ho1 = (t & 1) ? hA1 : hB1;
            lstm_step2<64><<<dim3(4,32,2), 256, 0, stream>>>(
                xgT0 + (size_t)t*SLAB,      tWhh,  hi0, ho0, c0,
                title_out + t*1024, 40*1024,
                xgT1 + (size_t)(39-t)*SLAB, tWhh1, hi1, ho1, c1,
                title_out + (39-t)*1024 + 512, 40*1024);
        }
        // after step 39 live state: hA0/hA1 (+ c0/c1)

        // ---- body: chunked xg + 200 fwd steps (+1 bwd step fused into t=0) ----
        float* ringA = bodybuf;
        float* ringB = bodybuf + (size_t)C*SLAB;
        for (int kchunk = 0, tb = 0; tb < 200; ++kchunk, tb += C) {
            int L = (C < 200 - tb) ? C : (200 - tb);
            float* buf = full ? bodybuf : ((kchunk & 1) ? ringB : ringA);
            if (!full) {
                xg_gemm<<<dim3(L*4,32,1), 256, 0, stream>>>(
                    x, bWih, bbih, bbhh, buf,
                       bWih, bbih, bbhh, buf, tb, 40);
            }
            for (int t = tb; t < tb + L; ++t) {
                const float* slab = buf + (size_t)(full ? t : (t - tb))*SLAB;
                int s = 40 + t;
                float* hi = (s & 1) ? hB0 : hA0;
                float* ho = (s & 1) ? hA0 : hB0;
                if (t == 0) {
                    // dual: body fwd t=0 + body bwd single step (reads xgBb)
                    lstm_step2<64><<<dim3(4,32,2), 256, 0, stream>>>(
                        slab, bWhh,  hA0, hB0, c0, (float*)nullptr, 0,
                        xgBb, bWhh1, hA1, hB1, c1, body_last + 512, 1024);
                } else {
                    float* exp_ = (t == 199) ? body_last : (float*)nullptr;
                    lstm_step2<32><<<dim3(8,32,1), 256, 0, stream>>>(
                        slab, bWhh, hi, ho, c0, exp_, 1024,
                        slab, bWhh, hi, ho, c0, (float*)nullptr, 0);
                }
            }
        }
    } else {
        // ---- legacy fallback (small workspace): fused-x step kernels ----
        for (int t = 0; t < 40; ++t) {
            float* hi0 = (t & 1) ? hB0 : hA0;
            float* ho0 = (t & 1) ? hA0 : hB0;
            float* hi1 = (t & 1) ? hB1 : hA1;
            float* ho1 = (t & 1) ? hA1 : hB1;
            lstm_step<64><<<dim3(4,32,2), 256, 0, stream>>>(
                x,
                tWih,  tWhh,  tbih,        tbhh,        hi0, ho0, c0,
                title_out + t*1024,            40*1024, t,
                tWih1, tWhh1, tbih + 2048, tbhh + 2048, hi1, ho1, c1,
                title_out + (39 - t)*1024 + 512, 40*1024, 39 - t);
        }
        lstm_step<64><<<dim3(4,32,2), 256, 0, stream>>>(
            x,
            bWih,  bWhh,  bbih,        bbhh,        hA0, hB0, c0, (float*)nullptr, 0, 40,
            bWih1, bWhh1, bbih + 2048, bbhh + 2048, hA1, hB1, c1, body_last + 512, 1024, 239);
        for (int t = 1; t < 200; ++t) {
            int s = 40 + t;
            float* hi = (s & 1) ? hB0 : hA0;
            float* ho = (s & 1) ? hA0 : hB0;
            float* exp_ = (t == 199) ? body_last : (float*)nullptr;
            lstm_step<32><<<dim3(8,32,1), 256, 0, stream>>>(
                x,
                bWih, bWhh, bbih, bbhh, hi, ho, c0, exp_, 1024, 40 + t,
                nullptr, nullptr, nullptr, nullptr, nullptr, nullptr, nullptr,
                (float*)nullptr, 0, 0);
        }
    }

    // ---- attention + classifier ----
    gemm_bias_act<0><<<dim3(8,16), 256, 0, stream>>>(body_last, 1024, bilW, nullptr,
                                                     u_buf, 1024, 1024);
    attn_ctx<<<256, 256, 0, stream>>>(title_out, u_buf, bilb, attn_in);
    copy_rows<<<256, 256, 0, stream>>>(body_last, 1024, attn_in + 1024, 2048, 1024);
    copy_rows<<<256, 256, 0, stream>>>(title_out + 39*1024, 40*1024, out_cat, 2048, 1024);
    gemm_bias_act<1><<<dim3(8,16), 256, 0, stream>>>(attn_in, 2048, attnW, attnb,
                                                     out_cat + 1024, 2048, 2048);
    gemm_bias_act<0><<<dim3(8,8), 256, 0, stream>>>(out_cat, 2048, decW, decb,
                                                    ch, 512, 2048);
    final_cls<<<4, 64, 0, stream>>>(ch, clsW, clsb, (float*)d_out);
}